// Round 3
// baseline (142.063 us; speedup 1.0000x reference)
//
#include <hip/hip_runtime.h>
#include <math.h>

#define HH 2048
#define WW 2048
#define TILE_H 32
#define TILE_W 64
#define ROWS 34       // TILE_H + 2 halo rows
#define QC   17       // quad-columns staged per tile (68 cols; 0..65 used)
#define LSTRIDE 72    // floats per LDS row (288 B, 16B-aligned quads)
#define GRIDX 16      // 2048 / (2*TILE_W)
#define GRIDY 64      // 2048 / TILE_H
#define NBLOCKS (GRIDX * GRIDY)   // 1024 blocks = exactly 4 per CU
#define NITEMS (ROWS * QC)        // 578 quad-slots per tile

// v_rcp_f32: ~1 ulp relative error — absmax threshold is 0.28, so free.
__device__ __forceinline__ float rcpf(float x) { return __builtin_amdgcn_rcpf(x); }

__device__ int g_ticket = 0;   // static-init 0 at module load; last block re-arms it

struct StageRegs {
    float4 E, V, A, B, C;
    int r, q;
    bool ld;
};

// Issue all 15 dwordx4 loads for one 34x68 tile (3 reg-sets per thread).
__device__ __forceinline__ void stage_load(
    const float* __restrict__ pred_E, const float* __restrict__ pred_v,
    const float* __restrict__ strain, int r0, int c0, int tid, StageRegs R[3])
{
    #pragma unroll
    for (int it = 0; it < 3; ++it) {
        const int idx = tid + it * 256;
        const int r = idx / QC;
        const int q = idx - r * QC;
        R[it].r = r; R[it].q = q;
        const int gi = r0 + r;
        const int gc = c0 + q * 4;
        const bool a = (idx < NITEMS) && (gi < HH) && (gc < WW);
        R[it].ld = a;
        if (a) {
            const int g = gi * WW + gc;
            R[it].E = *(const float4*)(pred_E + g);
            R[it].V = *(const float4*)(pred_v + g);
            const float* sp = strain + 3 * g;
            R[it].A = *(const float4*)(sp);
            R[it].B = *(const float4*)(sp + 4);
            R[it].C = *(const float4*)(sp + 8);
        }
    }
}

// Plane-stress math + LDS store; accumulates interior sum(E).
__device__ __forceinline__ void stage_math_store(
    StageRegs R[3], float& sumE,
    float (*sE)[LSTRIDE], float (*sxx)[LSTRIDE],
    float (*syy)[LSTRIDE], float (*sxy)[LSTRIDE])
{
    #pragma unroll
    for (int it = 0; it < 3; ++it) {
        if (R[it].ld) {
            const int r = R[it].r, q = R[it].q;
            const float e[4]  = {R[it].E.x, R[it].E.y, R[it].E.z, R[it].E.w};
            const float vv[4] = {R[it].V.x, R[it].V.y, R[it].V.z, R[it].V.w};
            const float s0[4] = {R[it].A.x, R[it].A.w, R[it].B.z, R[it].C.y};
            const float s1[4] = {R[it].A.y, R[it].B.x, R[it].B.w, R[it].C.z};
            const float s2[4] = {R[it].A.z, R[it].B.y, R[it].C.x, R[it].C.w};
            float xx[4], yy[4], xy[4];
            #pragma unroll
            for (int p = 0; p < 4; ++p) {
                const float v  = vv[p];
                const float fr = e[p] * rcpf(1.f - v * v);
                xx[p] = (s0[p] + v * s1[p]) * fr;
                yy[p] = (v * s0[p] + s1[p]) * fr;
                xy[p] = (s2[p] * (1.f - v) * 0.5f) * fr;
            }
            const int cq = 4 * q;
            *(float4*)&sE [r][cq] = R[it].E;
            *(float4*)&sxx[r][cq] = make_float4(xx[0], xx[1], xx[2], xx[3]);
            *(float4*)&syy[r][cq] = make_float4(yy[0], yy[1], yy[2], yy[3]);
            *(float4*)&sxy[r][cq] = make_float4(xy[0], xy[1], xy[2], xy[3]);
            if (r < TILE_H && q < 16)   // exclusive 32x64 interior: each pixel once
                sumE += e[0] + e[1] + e[2] + e[3];
        }
    }
}

// One row's 7 sliding-window values at column tx.
__device__ __forceinline__ void row7(
    int r, int tx, float* o,
    const float (*sE)[LSTRIDE], const float (*sxx)[LSTRIDE],
    const float (*syy)[LSTRIDE], const float (*sxy)[LSTRIDE])
{
    o[0] = sE [r][tx] + sE [r][tx + 1] + sE [r][tx + 2];   // E row-sum
    o[1] = sxx[r][tx] + sxx[r][tx + 1] + sxx[r][tx + 2];   // sxx row-sum
    const float l = sxy[r][tx], m = sxy[r][tx + 1], rg = sxy[r][tx + 2];
    o[2] = l + m + rg;                                     // sxy row-sum
    o[3] = l;                                              // sxy left col
    o[4] = rg;                                             // sxy right col
    o[5] = syy[r][tx];                                     // syy left col
    o[6] = syy[r][tx + 2];                                 // syy right col
}

// 3x3 stencils via 3-row sliding window; each thread: 8 output rows at col tx.
__device__ __forceinline__ void stencil(
    int r0, int c0, int tid, float& ax, float& ay,
    const float (*sE)[LSTRIDE], const float (*sxx)[LSTRIDE],
    const float (*syy)[LSTRIDE], const float (*sxy)[LSTRIDE])
{
    const int tx = tid & 63;
    const int ty = tid >> 6;
    const int lb = ty * 8;

    float w0[7], w1[7], w2[7];
    row7(lb + 0, tx, w0, sE, sxx, syy, sxy);
    row7(lb + 1, tx, w1, sE, sxx, syy, sxy);

    const bool cok = (c0 + tx) < (WW - 2);
    #pragma unroll
    for (int k = 0; k < 8; ++k) {
        row7(lb + k + 2, tx, w2, sE, sxx, syy, sxy);
        const int gi = r0 + lb + k;
        if (cok && gi < (HH - 2)) {
            const float rEc = rcpf(w0[0] + w1[0] + w2[0]);
            const float fx = (w2[1] - w0[1])
                           + (w0[3] + w1[3] + w2[3])
                           - (w0[4] + w1[4] + w2[4]);
            const float fy = (w0[5] + w1[5] + w2[5])
                           - (w0[6] + w1[6] + w2[6])
                           + (w2[2] - w0[2]);
            ax += fabsf(fx) * rEc;
            ay += fabsf(fy) * rEc;
        }
        #pragma unroll
        for (int j = 0; j < 7; ++j) { w0[j] = w1[j]; w1[j] = w2[j]; }
    }
}

// Partials in d_ws: [0..1023]=sum|fx/Ec|, [1024..2047]=sum|fy/Ec|, [2048..3071]=sumE
__global__ __launch_bounds__(256, 4) void fused_loss_kernel(
    const float* __restrict__ pred_E,
    const float* __restrict__ pred_v,
    const float* __restrict__ strain,
    float* __restrict__ part,
    float* __restrict__ out)
{
    __shared__ float sE [ROWS][LSTRIDE];
    __shared__ float sxx[ROWS][LSTRIDE];
    __shared__ float syy[ROWS][LSTRIDE];
    __shared__ float sxy[ROWS][LSTRIDE];
    __shared__ float red[3][4];
    __shared__ int   is_last;

    const int tid = threadIdx.x;
    const int r0 = blockIdx.y * TILE_H;
    const int c0 = blockIdx.x * (2 * TILE_W);   // tile pair: c0 and c0+64

    float sumE = 0.f, ax = 0.f, ay = 0.f;
    StageRegs R0[3], R1[3];

    // ---- software pipeline across the two tiles ----
    stage_load(pred_E, pred_v, strain, r0, c0, tid, R0);            // t0: 15 dwordx4
    stage_math_store(R0, sumE, sE, sxx, syy, sxy);                  // t0 math -> LDS
    __syncthreads();
    stage_load(pred_E, pred_v, strain, r0, c0 + TILE_W, tid, R1);   // t1 loads in flight
    stencil(r0, c0, tid, ax, ay, sE, sxx, syy, sxy);                // t0 stencil overlaps t1 loads
    __syncthreads();                                                // t0 LDS reads done
    stage_math_store(R1, sumE, sE, sxx, syy, sxy);                  // t1 math -> LDS
    __syncthreads();
    stencil(r0, c0 + TILE_W, tid, ax, ay, sE, sxx, syy, sxy);       // t1 stencil

    // ---- block reduction -> per-block partials ----
    #pragma unroll
    for (int off = 32; off > 0; off >>= 1) {
        ax   += __shfl_down(ax, off);
        ay   += __shfl_down(ay, off);
        sumE += __shfl_down(sumE, off);
    }
    const int wave = tid >> 6, lane = tid & 63;
    if (lane == 0) { red[0][wave] = ax; red[1][wave] = ay; red[2][wave] = sumE; }
    __syncthreads();
    if (tid == 0) {
        const int b = blockIdx.y * GRIDX + blockIdx.x;
        part[b]               = red[0][0] + red[0][1] + red[0][2] + red[0][3];
        part[NBLOCKS + b]     = red[1][0] + red[1][1] + red[1][2] + red[1][3];
        part[2 * NBLOCKS + b] = red[2][0] + red[2][1] + red[2][2] + red[2][3];
        __threadfence();   // partials visible device-wide before ticket bump
        const int old = atomicAdd(&g_ticket, 1);   // device-scope by default
        is_last = (old == NBLOCKS - 1);
    }
    __syncthreads();

    // ---- last block finishes: reduce 3x1024 partials, write scalar loss ----
    if (is_last) {
        __threadfence();   // acquire side: see all blocks' partials
        const float4* px = (const float4*)(part);
        const float4* py = (const float4*)(part + NBLOCKS);
        const float4* pe = (const float4*)(part + 2 * NBLOCKS);
        const float4 a = px[tid], b2 = py[tid], c = pe[tid];   // 256 f4 per plane
        float x = a.x + a.y + a.z + a.w;
        float y = b2.x + b2.y + b2.z + b2.w;
        float e = c.x + c.y + c.z + c.w;
        #pragma unroll
        for (int off = 32; off > 0; off >>= 1) {
            x += __shfl_down(x, off);
            y += __shfl_down(y, off);
            e += __shfl_down(e, off);
        }
        __syncthreads();   // red[] reuse after earlier phase
        if (lane == 0) { red[0][wave] = x; red[1][wave] = y; red[2][wave] = e; }
        __syncthreads();
        if (tid == 0) {
            const float rx = red[0][0] + red[0][1] + red[0][2] + red[0][3];
            const float ry = red[1][0] + red[1][1] + red[1][2] + red[1][3];
            const float re = red[2][0] + red[2][1] + red[2][2] + red[2][3];
            const float M = (float)((HH - 2) * (WW - 2));
            out[0] = rx / M + ry / M + fabsf(re / (float)(HH * WW) - 1.0f) * 0.01f;
            atomicExch(&g_ticket, 0);   // re-arm for next graph replay
        }
    }
}

extern "C" void kernel_launch(void* const* d_in, const int* in_sizes, int n_in,
                              void* d_out, int out_size, void* d_ws, size_t ws_size,
                              hipStream_t stream) {
    const float* pred_E = (const float*)d_in[0];
    const float* pred_v = (const float*)d_in[1];
    const float* strain = (const float*)d_in[2];
    float* out  = (float*)d_out;
    float* part = (float*)d_ws;   // 3 * 1024 floats = 12 KB

    dim3 grid(GRIDX, GRIDY);      // 16 x 64 = 1024 blocks, exactly 4/CU resident
    fused_loss_kernel<<<grid, 256, 0, stream>>>(pred_E, pred_v, strain, part, out);
}

// Round 4
// 110.001 us; speedup vs baseline: 1.2915x; 1.2915x over previous
//
#include <hip/hip_runtime.h>
#include <math.h>

#define HH 2048
#define WW 2048
#define TILE_H 32
#define TILE_W 64
#define ROWS 34       // TILE_H + 2 halo rows
#define QC   17       // quad-columns staged per tile (68 cols; 0..65 used)
#define LSTRIDE 72    // floats per LDS row (288 B, 16B-aligned quads)
#define GRIDX 16      // 2048 / (2*TILE_W)
#define GRIDY 64      // 2048 / TILE_H
#define NBLOCKS (GRIDX * GRIDY)   // 1024 blocks = exactly 4 per CU, zero tail
#define NITEMS (ROWS * QC)        // 578 quad-slots per tile

// v_rcp_f32: ~1 ulp relative error — absmax threshold is 0.28, so free.
__device__ __forceinline__ float rcpf(float x) { return __builtin_amdgcn_rcpf(x); }

struct StageRegs {
    float4 E, V, A, B, C;
    int r, q;
    bool ld;
};

// Issue all 15 dwordx4 loads for one 34x68 tile (3 reg-sets per thread).
__device__ __forceinline__ void stage_load(
    const float* __restrict__ pred_E, const float* __restrict__ pred_v,
    const float* __restrict__ strain, int r0, int c0, int tid, StageRegs R[3])
{
    #pragma unroll
    for (int it = 0; it < 3; ++it) {
        const int idx = tid + it * 256;
        const int r = idx / QC;
        const int q = idx - r * QC;
        R[it].r = r; R[it].q = q;
        const int gi = r0 + r;
        const int gc = c0 + q * 4;
        const bool a = (idx < NITEMS) && (gi < HH) && (gc < WW);
        R[it].ld = a;
        if (a) {
            const int g = gi * WW + gc;
            R[it].E = *(const float4*)(pred_E + g);
            R[it].V = *(const float4*)(pred_v + g);
            const float* sp = strain + 3 * g;
            R[it].A = *(const float4*)(sp);
            R[it].B = *(const float4*)(sp + 4);
            R[it].C = *(const float4*)(sp + 8);
        }
    }
}

// Plane-stress math + LDS store; accumulates interior sum(E).
__device__ __forceinline__ void stage_math_store(
    StageRegs R[3], float& sumE,
    float (*sE)[LSTRIDE], float (*sxx)[LSTRIDE],
    float (*syy)[LSTRIDE], float (*sxy)[LSTRIDE])
{
    #pragma unroll
    for (int it = 0; it < 3; ++it) {
        if (R[it].ld) {
            const int r = R[it].r, q = R[it].q;
            const float e[4]  = {R[it].E.x, R[it].E.y, R[it].E.z, R[it].E.w};
            const float vv[4] = {R[it].V.x, R[it].V.y, R[it].V.z, R[it].V.w};
            const float s0[4] = {R[it].A.x, R[it].A.w, R[it].B.z, R[it].C.y};
            const float s1[4] = {R[it].A.y, R[it].B.x, R[it].B.w, R[it].C.z};
            const float s2[4] = {R[it].A.z, R[it].B.y, R[it].C.x, R[it].C.w};
            float xx[4], yy[4], xy[4];
            #pragma unroll
            for (int p = 0; p < 4; ++p) {
                const float v  = vv[p];
                const float fr = e[p] * rcpf(1.f - v * v);
                xx[p] = (s0[p] + v * s1[p]) * fr;
                yy[p] = (v * s0[p] + s1[p]) * fr;
                xy[p] = (s2[p] * (1.f - v) * 0.5f) * fr;
            }
            const int cq = 4 * q;
            *(float4*)&sE [r][cq] = R[it].E;
            *(float4*)&sxx[r][cq] = make_float4(xx[0], xx[1], xx[2], xx[3]);
            *(float4*)&syy[r][cq] = make_float4(yy[0], yy[1], yy[2], yy[3]);
            *(float4*)&sxy[r][cq] = make_float4(xy[0], xy[1], xy[2], xy[3]);
            if (r < TILE_H && q < 16)   // exclusive 32x64 interior: each pixel once
                sumE += e[0] + e[1] + e[2] + e[3];
        }
    }
}

// One row's 7 sliding-window values at column tx.
__device__ __forceinline__ void row7(
    int r, int tx, float* o,
    const float (*sE)[LSTRIDE], const float (*sxx)[LSTRIDE],
    const float (*syy)[LSTRIDE], const float (*sxy)[LSTRIDE])
{
    o[0] = sE [r][tx] + sE [r][tx + 1] + sE [r][tx + 2];   // E row-sum
    o[1] = sxx[r][tx] + sxx[r][tx + 1] + sxx[r][tx + 2];   // sxx row-sum
    const float l = sxy[r][tx], m = sxy[r][tx + 1], rg = sxy[r][tx + 2];
    o[2] = l + m + rg;                                     // sxy row-sum
    o[3] = l;                                              // sxy left col
    o[4] = rg;                                             // sxy right col
    o[5] = syy[r][tx];                                     // syy left col
    o[6] = syy[r][tx + 2];                                 // syy right col
}

// 3x3 stencils via 3-row sliding window; each thread: 8 output rows at col tx.
__device__ __forceinline__ void stencil(
    int r0, int c0, int tid, float& ax, float& ay,
    const float (*sE)[LSTRIDE], const float (*sxx)[LSTRIDE],
    const float (*syy)[LSTRIDE], const float (*sxy)[LSTRIDE])
{
    const int tx = tid & 63;
    const int ty = tid >> 6;
    const int lb = ty * 8;

    float w0[7], w1[7], w2[7];
    row7(lb + 0, tx, w0, sE, sxx, syy, sxy);
    row7(lb + 1, tx, w1, sE, sxx, syy, sxy);

    const bool cok = (c0 + tx) < (WW - 2);
    #pragma unroll
    for (int k = 0; k < 8; ++k) {
        row7(lb + k + 2, tx, w2, sE, sxx, syy, sxy);
        const int gi = r0 + lb + k;
        if (cok && gi < (HH - 2)) {
            const float rEc = rcpf(w0[0] + w1[0] + w2[0]);
            const float fx = (w2[1] - w0[1])
                           + (w0[3] + w1[3] + w2[3])
                           - (w0[4] + w1[4] + w2[4]);
            const float fy = (w0[5] + w1[5] + w2[5])
                           - (w0[6] + w1[6] + w2[6])
                           + (w2[2] - w0[2]);
            ax += fabsf(fx) * rEc;
            ay += fabsf(fy) * rEc;
        }
        #pragma unroll
        for (int j = 0; j < 7; ++j) { w0[j] = w1[j]; w1[j] = w2[j]; }
    }
}

// Partials in d_ws: [0..1023]=sum|fx/Ec|, [1024..2047]=sum|fy/Ec|, [2048..3071]=sumE
__global__ __launch_bounds__(256, 4) void fused_loss_kernel(
    const float* __restrict__ pred_E,
    const float* __restrict__ pred_v,
    const float* __restrict__ strain,
    float* __restrict__ part)
{
    __shared__ float sE [ROWS][LSTRIDE];
    __shared__ float sxx[ROWS][LSTRIDE];
    __shared__ float syy[ROWS][LSTRIDE];
    __shared__ float sxy[ROWS][LSTRIDE];
    __shared__ float red[3][4];

    const int tid = threadIdx.x;
    const int r0 = blockIdx.y * TILE_H;
    const int c0 = blockIdx.x * (2 * TILE_W);   // tile pair: c0 and c0+64

    float sumE = 0.f, ax = 0.f, ay = 0.f;
    StageRegs R0[3], R1[3];

    // ---- software pipeline across the two tiles ----
    stage_load(pred_E, pred_v, strain, r0, c0, tid, R0);            // t0: 15 dwordx4
    stage_math_store(R0, sumE, sE, sxx, syy, sxy);                  // t0 math -> LDS
    __syncthreads();
    stage_load(pred_E, pred_v, strain, r0, c0 + TILE_W, tid, R1);   // t1 loads in flight
    stencil(r0, c0, tid, ax, ay, sE, sxx, syy, sxy);                // t0 stencil overlaps t1 loads
    __syncthreads();                                                // t0 LDS reads done
    stage_math_store(R1, sumE, sE, sxx, syy, sxy);                  // t1 math -> LDS
    __syncthreads();
    stencil(r0, c0 + TILE_W, tid, ax, ay, sE, sxx, syy, sxy);       // t1 stencil

    // ---- block reduction -> per-block partials (plain stores, no atomics) ----
    #pragma unroll
    for (int off = 32; off > 0; off >>= 1) {
        ax   += __shfl_down(ax, off);
        ay   += __shfl_down(ay, off);
        sumE += __shfl_down(sumE, off);
    }
    const int wave = tid >> 6, lane = tid & 63;
    if (lane == 0) { red[0][wave] = ax; red[1][wave] = ay; red[2][wave] = sumE; }
    __syncthreads();
    if (tid == 0) {
        const int b = blockIdx.y * GRIDX + blockIdx.x;
        part[b]               = red[0][0] + red[0][1] + red[0][2] + red[0][3];
        part[NBLOCKS + b]     = red[1][0] + red[1][1] + red[1][2] + red[1][3];
        part[2 * NBLOCKS + b] = red[2][0] + red[2][1] + red[2][2] + red[2][3];
    }
}

__global__ __launch_bounds__(256) void finalize_kernel(
    const float* __restrict__ part, float* __restrict__ out)
{
    const int tid = threadIdx.x;
    const float4* px = (const float4*)(part);
    const float4* py = (const float4*)(part + NBLOCKS);
    const float4* pe = (const float4*)(part + 2 * NBLOCKS);
    // 1024 floats per plane = 256 float4 per plane; one per thread.
    const float4 a = px[tid], b = py[tid], c = pe[tid];
    float x = a.x + a.y + a.z + a.w;
    float y = b.x + b.y + b.z + b.w;
    float e = c.x + c.y + c.z + c.w;
    #pragma unroll
    for (int off = 32; off > 0; off >>= 1) {
        x += __shfl_down(x, off);
        y += __shfl_down(y, off);
        e += __shfl_down(e, off);
    }
    __shared__ float red[3][4];
    const int wave = tid >> 6, lane = tid & 63;
    if (lane == 0) { red[0][wave] = x; red[1][wave] = y; red[2][wave] = e; }
    __syncthreads();
    if (tid == 0) {
        const float rx = red[0][0] + red[0][1] + red[0][2] + red[0][3];
        const float ry = red[1][0] + red[1][1] + red[1][2] + red[1][3];
        const float re = red[2][0] + red[2][1] + red[2][2] + red[2][3];
        const float M = (float)((HH - 2) * (WW - 2));
        const float loss_x = rx / M;
        const float loss_y = ry / M;
        const float loss_e = fabsf(re / (float)(HH * WW) - 1.0f);
        out[0] = loss_x + loss_y + loss_e * 0.01f;
    }
}

extern "C" void kernel_launch(void* const* d_in, const int* in_sizes, int n_in,
                              void* d_out, int out_size, void* d_ws, size_t ws_size,
                              hipStream_t stream) {
    const float* pred_E = (const float*)d_in[0];
    const float* pred_v = (const float*)d_in[1];
    const float* strain = (const float*)d_in[2];
    float* out  = (float*)d_out;
    float* part = (float*)d_ws;   // 3 * 1024 floats = 12 KB

    dim3 grid(GRIDX, GRIDY);      // 16 x 64 = 1024 blocks, exactly 4/CU resident
    fused_loss_kernel<<<grid, 256, 0, stream>>>(pred_E, pred_v, strain, part);
    finalize_kernel<<<1, 256, 0, stream>>>(part, out);
}

// Round 5
// 108.392 us; speedup vs baseline: 1.3106x; 1.0148x over previous
//
#include <hip/hip_runtime.h>
#include <math.h>

#define HH 2048
#define WW 2048
#define TILE_H 16
#define TILE_W 64
#define ROWS 18       // TILE_H + 2 halo rows
#define QC   17       // quad-columns staged (68 cols; 0..65 used)
#define LSTRIDE 68    // floats per LDS row (272 B, quad-aligned, rotates banks by 4/row)
#define GRIDX 32      // 2048 / TILE_W
#define GRIDY 128     // 2048 / TILE_H
#define NBLOCKS (GRIDX * GRIDY)   // 4096 blocks; 8/CU resident -> 2 generations
#define NITEMS (ROWS * QC)        // 306 quad-slots per tile

// v_rcp_f32: ~1 ulp relative error — absmax threshold is 0.28, so free.
__device__ __forceinline__ float rcpf(float x) { return __builtin_amdgcn_rcpf(x); }

struct StageRegs {
    float4 E, V, A, B, C;
    int r, q;
    bool ld;
};

// Issue all 10 dwordx4 loads for one 18x68 tile (2 reg-sets per thread).
__device__ __forceinline__ void stage_load(
    const float* __restrict__ pred_E, const float* __restrict__ pred_v,
    const float* __restrict__ strain, int r0, int c0, int tid, StageRegs R[2])
{
    #pragma unroll
    for (int it = 0; it < 2; ++it) {
        const int idx = tid + it * 256;
        const int r = idx / QC;
        const int q = idx - r * QC;
        R[it].r = r; R[it].q = q;
        const int gi = r0 + r;
        const int gc = c0 + q * 4;
        const bool a = (idx < NITEMS) && (gi < HH) && (gc < WW);
        R[it].ld = a;
        if (a) {
            const int g = gi * WW + gc;
            R[it].E = *(const float4*)(pred_E + g);
            R[it].V = *(const float4*)(pred_v + g);
            const float* sp = strain + 3 * g;
            R[it].A = *(const float4*)(sp);
            R[it].B = *(const float4*)(sp + 4);
            R[it].C = *(const float4*)(sp + 8);
        }
    }
}

// Plane-stress math + LDS store; accumulates interior sum(E).
__device__ __forceinline__ void stage_math_store(
    StageRegs R[2], float& sumE,
    float (*sE)[LSTRIDE], float (*sxx)[LSTRIDE],
    float (*syy)[LSTRIDE], float (*sxy)[LSTRIDE])
{
    #pragma unroll
    for (int it = 0; it < 2; ++it) {
        if (R[it].ld) {
            const int r = R[it].r, q = R[it].q;
            const float e[4]  = {R[it].E.x, R[it].E.y, R[it].E.z, R[it].E.w};
            const float vv[4] = {R[it].V.x, R[it].V.y, R[it].V.z, R[it].V.w};
            const float s0[4] = {R[it].A.x, R[it].A.w, R[it].B.z, R[it].C.y};
            const float s1[4] = {R[it].A.y, R[it].B.x, R[it].B.w, R[it].C.z};
            const float s2[4] = {R[it].A.z, R[it].B.y, R[it].C.x, R[it].C.w};
            float xx[4], yy[4], xy[4];
            #pragma unroll
            for (int p = 0; p < 4; ++p) {
                const float v  = vv[p];
                const float fr = e[p] * rcpf(1.f - v * v);
                xx[p] = (s0[p] + v * s1[p]) * fr;
                yy[p] = (v * s0[p] + s1[p]) * fr;
                xy[p] = (s2[p] * (1.f - v) * 0.5f) * fr;
            }
            const int cq = 4 * q;
            *(float4*)&sE [r][cq] = R[it].E;
            *(float4*)&sxx[r][cq] = make_float4(xx[0], xx[1], xx[2], xx[3]);
            *(float4*)&syy[r][cq] = make_float4(yy[0], yy[1], yy[2], yy[3]);
            *(float4*)&sxy[r][cq] = make_float4(xy[0], xy[1], xy[2], xy[3]);
            if (r < TILE_H && q < 16)   // exclusive 16x64 interior: each pixel once
                sumE += e[0] + e[1] + e[2] + e[3];
        }
    }
}

// One row's 7 sliding-window values at column tx.
__device__ __forceinline__ void row7(
    int r, int tx, float* o,
    const float (*sE)[LSTRIDE], const float (*sxx)[LSTRIDE],
    const float (*syy)[LSTRIDE], const float (*sxy)[LSTRIDE])
{
    o[0] = sE [r][tx] + sE [r][tx + 1] + sE [r][tx + 2];   // E row-sum
    o[1] = sxx[r][tx] + sxx[r][tx + 1] + sxx[r][tx + 2];   // sxx row-sum
    const float l = sxy[r][tx], m = sxy[r][tx + 1], rg = sxy[r][tx + 2];
    o[2] = l + m + rg;                                     // sxy row-sum
    o[3] = l;                                              // sxy left col
    o[4] = rg;                                             // sxy right col
    o[5] = syy[r][tx];                                     // syy left col
    o[6] = syy[r][tx + 2];                                 // syy right col
}

// 3x3 stencils via 3-row sliding window; each thread: 4 output rows at col tx.
__device__ __forceinline__ void stencil(
    int r0, int c0, int tid, float& ax, float& ay,
    const float (*sE)[LSTRIDE], const float (*sxx)[LSTRIDE],
    const float (*syy)[LSTRIDE], const float (*sxy)[LSTRIDE])
{
    const int tx = tid & 63;
    const int ty = tid >> 6;
    const int lb = ty * 4;

    float w0[7], w1[7], w2[7];
    row7(lb + 0, tx, w0, sE, sxx, syy, sxy);
    row7(lb + 1, tx, w1, sE, sxx, syy, sxy);

    const bool cok = (c0 + tx) < (WW - 2);
    #pragma unroll
    for (int k = 0; k < 4; ++k) {
        row7(lb + k + 2, tx, w2, sE, sxx, syy, sxy);
        const int gi = r0 + lb + k;
        if (cok && gi < (HH - 2)) {
            const float rEc = rcpf(w0[0] + w1[0] + w2[0]);
            const float fx = (w2[1] - w0[1])
                           + (w0[3] + w1[3] + w2[3])
                           - (w0[4] + w1[4] + w2[4]);
            const float fy = (w0[5] + w1[5] + w2[5])
                           - (w0[6] + w1[6] + w2[6])
                           + (w2[2] - w0[2]);
            ax += fabsf(fx) * rEc;
            ay += fabsf(fy) * rEc;
        }
        #pragma unroll
        for (int j = 0; j < 7; ++j) { w0[j] = w1[j]; w1[j] = w2[j]; }
    }
}

// Partials in d_ws: [0..4095]=sum|fx/Ec|, [4096..8191]=sum|fy/Ec|, [8192..12287]=sumE
__global__ __launch_bounds__(256, 8) void fused_loss_kernel(
    const float* __restrict__ pred_E,
    const float* __restrict__ pred_v,
    const float* __restrict__ strain,
    float* __restrict__ part)
{
    __shared__ float sE [ROWS][LSTRIDE];
    __shared__ float sxx[ROWS][LSTRIDE];
    __shared__ float syy[ROWS][LSTRIDE];
    __shared__ float sxy[ROWS][LSTRIDE];
    __shared__ float red[3][4];

    const int tid = threadIdx.x;
    const int r0 = blockIdx.y * TILE_H;
    const int c0 = blockIdx.x * TILE_W;

    float sumE = 0.f, ax = 0.f, ay = 0.f;
    StageRegs R[2];

    stage_load(pred_E, pred_v, strain, r0, c0, tid, R);   // 10 dwordx4 in flight
    stage_math_store(R, sumE, sE, sxx, syy, sxy);
    __syncthreads();
    stencil(r0, c0, tid, ax, ay, sE, sxx, syy, sxy);

    // ---- block reduction -> per-block partials ----
    #pragma unroll
    for (int off = 32; off > 0; off >>= 1) {
        ax   += __shfl_down(ax, off);
        ay   += __shfl_down(ay, off);
        sumE += __shfl_down(sumE, off);
    }
    const int wave = tid >> 6, lane = tid & 63;
    if (lane == 0) { red[0][wave] = ax; red[1][wave] = ay; red[2][wave] = sumE; }
    __syncthreads();
    if (tid == 0) {
        const int b = blockIdx.y * GRIDX + blockIdx.x;
        part[b]               = red[0][0] + red[0][1] + red[0][2] + red[0][3];
        part[NBLOCKS + b]     = red[1][0] + red[1][1] + red[1][2] + red[1][3];
        part[2 * NBLOCKS + b] = red[2][0] + red[2][1] + red[2][2] + red[2][3];
    }
}

__global__ __launch_bounds__(256) void finalize_kernel(
    const float* __restrict__ part, float* __restrict__ out)
{
    const int tid = threadIdx.x;
    const float4* px = (const float4*)(part);
    const float4* py = (const float4*)(part + NBLOCKS);
    const float4* pe = (const float4*)(part + 2 * NBLOCKS);
    float x = 0.f, y = 0.f, e = 0.f;
    #pragma unroll
    for (int k = 0; k < 4; ++k) {          // 1024 float4 per plane / 256 threads
        const int i = tid + k * 256;
        const float4 a = px[i], b = py[i], c = pe[i];
        x += a.x + a.y + a.z + a.w;
        y += b.x + b.y + b.z + b.w;
        e += c.x + c.y + c.z + c.w;
    }
    #pragma unroll
    for (int off = 32; off > 0; off >>= 1) {
        x += __shfl_down(x, off);
        y += __shfl_down(y, off);
        e += __shfl_down(e, off);
    }
    __shared__ float red[3][4];
    const int wave = tid >> 6, lane = tid & 63;
    if (lane == 0) { red[0][wave] = x; red[1][wave] = y; red[2][wave] = e; }
    __syncthreads();
    if (tid == 0) {
        const float rx = red[0][0] + red[0][1] + red[0][2] + red[0][3];
        const float ry = red[1][0] + red[1][1] + red[1][2] + red[1][3];
        const float re = red[2][0] + red[2][1] + red[2][2] + red[2][3];
        const float M = (float)((HH - 2) * (WW - 2));
        const float loss_x = rx / M;
        const float loss_y = ry / M;
        const float loss_e = fabsf(re / (float)(HH * WW) - 1.0f);
        out[0] = loss_x + loss_y + loss_e * 0.01f;
    }
}

extern "C" void kernel_launch(void* const* d_in, const int* in_sizes, int n_in,
                              void* d_out, int out_size, void* d_ws, size_t ws_size,
                              hipStream_t stream) {
    const float* pred_E = (const float*)d_in[0];
    const float* pred_v = (const float*)d_in[1];
    const float* strain = (const float*)d_in[2];
    float* out  = (float*)d_out;
    float* part = (float*)d_ws;   // 3 * 4096 floats = 48 KB

    dim3 grid(GRIDX, GRIDY);      // 32 x 128 = 4096 blocks; 8/CU resident, 2 gens
    fused_loss_kernel<<<grid, 256, 0, stream>>>(pred_E, pred_v, strain, part);
    finalize_kernel<<<1, 256, 0, stream>>>(part, out);
}